// Round 1
// baseline (197.035 us; speedup 1.0000x reference)
//
#include <hip/hip_runtime.h>
#include <hip/hip_bf16.h>
#include <stdint.h>

#define KDIM 4096
#define BM 128
#define BN 128
#define BK 32

typedef __attribute__((ext_vector_type(8))) short bf16x8;
typedef __attribute__((ext_vector_type(4))) float f32x4;

__device__ inline unsigned short f2bf_bits(float f) {
  __hip_bfloat16 h = __float2bfloat16(f);
  union { __hip_bfloat16 h; unsigned short u; } cv;
  cv.h = h;
  return cv.u;
}

// Replicates: scaled = t / bm * 6; q = sign * nearest_palette(|scaled|) (ties -> lower);
// dq = q * (bm/6), then round to bf16.
__device__ inline unsigned short qdq(float t, float bm, float scale) {
  float s = t / bm;       // same op order as reference: tb / block_max * 6
  s = s * 6.0f;
  float a = fabsf(s);
  float v;
  if (a <= 0.25f)      v = 0.0f;
  else if (a <= 0.75f) v = 0.5f;
  else if (a <= 1.25f) v = 1.0f;
  else if (a <= 1.75f) v = 1.5f;
  else if (a <= 2.5f)  v = 2.0f;
  else if (a <= 3.5f)  v = 3.0f;
  else if (a <= 5.0f)  v = 4.0f;
  else                 v = 6.0f;
  float q = copysignf(v, s);
  return f2bf_bits(q * scale);
}

// One 8-lane subgroup handles one 32-element block: float4 per lane, shfl_xor max.
__global__ void nvfp4_quant_dq(const float* __restrict__ in,
                               unsigned short* __restrict__ out, int n_sub) {
  int gid = blockIdx.x * blockDim.x + threadIdx.x;
  int sub = gid >> 3;
  if (sub >= n_sub) return;
  int l8 = gid & 7;
  long base = (long)sub * 32 + (long)l8 * 4;
  const float4 v = *(const float4*)(in + base);
  float amax = fmaxf(fmaxf(fabsf(v.x), fabsf(v.y)), fmaxf(fabsf(v.z), fabsf(v.w)));
  amax = fmaxf(amax, __shfl_xor(amax, 1));
  amax = fmaxf(amax, __shfl_xor(amax, 2));
  amax = fmaxf(amax, __shfl_xor(amax, 4));
  float bm = fmaxf(amax, 1e-12f);   // jnp.clip(max, 1e-12)
  float scale = bm / 6.0f;          // block scale (fp32)
  ushort4 o;
  o.x = qdq(v.x, bm, scale);
  o.y = qdq(v.y, bm, scale);
  o.z = qdq(v.z, bm, scale);
  o.w = qdq(v.w, bm, scale);
  *(ushort4*)(out + base) = o;
}

// m97-style GEMM: C[M,N] = A[M,K](bf16) * B[N,K]^T(bf16), 128x128 tile, BK=32,
// 4 waves (2x2), each wave 64x64 via 4x4 grid of 16x16x32 MFMA.
__global__ __launch_bounds__(256, 1) void gemm_bf16_bt(
    const unsigned short* __restrict__ A,  // [M, K]
    const unsigned short* __restrict__ B,  // [N, K]
    float* __restrict__ C, int M, int N) {
  __shared__ unsigned short As[BM * BK];
  __shared__ unsigned short Bs[BN * BK];

  const int tid = threadIdx.x;
  const int wave = tid >> 6;
  const int lane = tid & 63;
  const int wm = wave >> 1;       // 0..1
  const int wn = wave & 1;        // 0..1
  const int quad = lane >> 4;     // 0..3
  const int r16 = lane & 15;      // 0..15

  const int bm0 = blockIdx.y * BM;
  const int bn0 = blockIdx.x * BN;

  // Staging: each wave issues 2 x 16B global_load_lds for A and 2 for B.
  // Chunk cc (0..7) = 1024 B = 16 rows x 64 B. Lane l covers row cc*16 + l/4,
  // k = (l&3)*8 .. +8.
  const int cc = wave * 2;
  const int rstg = lane >> 2;          // 0..15
  const int kstg = (lane & 3) * 8;     // 0,8,16,24

  const unsigned short* aptr0 = A + (long)(bm0 + cc * 16 + rstg) * KDIM + kstg;
  const unsigned short* aptr1 = aptr0 + 16 * KDIM;
  const unsigned short* bptr0 = B + (long)(bn0 + cc * 16 + rstg) * KDIM + kstg;
  const unsigned short* bptr1 = bptr0 + 16 * KDIM;

  unsigned short* lA0 = As + cc * 512 + lane * 8;
  unsigned short* lA1 = As + (cc + 1) * 512 + lane * 8;
  unsigned short* lB0 = Bs + cc * 512 + lane * 8;
  unsigned short* lB1 = Bs + (cc + 1) * 512 + lane * 8;

  f32x4 acc[4][4] = {};

  for (int k0 = 0; k0 < KDIM; k0 += BK) {
    __builtin_amdgcn_global_load_lds(
        (const __attribute__((address_space(1))) void*)aptr0,
        (__attribute__((address_space(3))) void*)lA0, 16, 0, 0);
    __builtin_amdgcn_global_load_lds(
        (const __attribute__((address_space(1))) void*)aptr1,
        (__attribute__((address_space(3))) void*)lA1, 16, 0, 0);
    __builtin_amdgcn_global_load_lds(
        (const __attribute__((address_space(1))) void*)bptr0,
        (__attribute__((address_space(3))) void*)lB0, 16, 0, 0);
    __builtin_amdgcn_global_load_lds(
        (const __attribute__((address_space(1))) void*)bptr1,
        (__attribute__((address_space(3))) void*)lB1, 16, 0, 0);
    aptr0 += BK; aptr1 += BK; bptr0 += BK; bptr1 += BK;

    __syncthreads();

    bf16x8 af[4], bf[4];
#pragma unroll
    for (int i = 0; i < 4; i++) {
      const int arow = wm * 64 + i * 16 + r16;
      af[i] = *(const bf16x8*)(As + arow * BK + quad * 8);
      const int brow = wn * 64 + i * 16 + r16;
      bf[i] = *(const bf16x8*)(Bs + brow * BK + quad * 8);
    }

#pragma unroll
    for (int i = 0; i < 4; i++)
#pragma unroll
      for (int j = 0; j < 4; j++)
        acc[i][j] = __builtin_amdgcn_mfma_f32_16x16x32_bf16(af[i], bf[j], acc[i][j], 0, 0, 0);

    __syncthreads();
  }

  // Epilogue: C/D layout col = lane&15, row = quad*4 + reg
#pragma unroll
  for (int i = 0; i < 4; i++) {
#pragma unroll
    for (int j = 0; j < 4; j++) {
      const int row = bm0 + wm * 64 + i * 16 + quad * 4;
      const int col = bn0 + wn * 64 + j * 16 + r16;
#pragma unroll
      for (int r = 0; r < 4; r++)
        C[(long)(row + r) * N + col] = acc[i][j][r];
    }
  }
}

extern "C" void kernel_launch(void* const* d_in, const int* in_sizes, int n_in,
                              void* d_out, int out_size, void* d_ws, size_t ws_size,
                              hipStream_t stream) {
  const float* x = (const float*)d_in[0];   // [M, K] fp32
  const float* w = (const float*)d_in[1];   // [N, K] fp32
  float* out = (float*)d_out;               // [M, N] fp32

  const int MK = in_sizes[0];
  const int NK = in_sizes[1];
  const int M = MK / KDIM;
  const int N = NK / KDIM;

  unsigned short* xq = (unsigned short*)d_ws;        // [M, K] bf16
  unsigned short* wq = xq + (size_t)MK;              // [N, K] bf16

  const int nsub_x = MK / 32;
  const int nsub_w = NK / 32;
  nvfp4_quant_dq<<<dim3((nsub_x * 8 + 255) / 256), dim3(256), 0, stream>>>(x, xq, nsub_x);
  nvfp4_quant_dq<<<dim3((nsub_w * 8 + 255) / 256), dim3(256), 0, stream>>>(w, wq, nsub_w);

  dim3 grid(N / BN, M / BM);
  gemm_bf16_bt<<<grid, dim3(256), 0, stream>>>(xq, wq, out, M, N);
}

// Round 2
// 176.279 us; speedup vs baseline: 1.1177x; 1.1177x over previous
//
#include <hip/hip_runtime.h>
#include <hip/hip_bf16.h>
#include <stdint.h>

#define KDIM 4096
#define BM 64
#define BN 128
#define BK 32

typedef __attribute__((ext_vector_type(8))) short bf16x8;
typedef __attribute__((ext_vector_type(4))) float f32x4;

__device__ inline unsigned short f2bf_bits(float f) {
  union { __hip_bfloat16 h; unsigned short u; } cv;
  cv.h = __float2bfloat16(f);
  return cv.u;
}

// Replicates: scaled = t / bm * 6; q = sign * nearest_palette(|scaled|) (ties -> lower);
// dq = q * (bm/6), rounded to bf16. Division kept exact (fp32 div) so palette
// boundary decisions bit-match the reference.
__device__ inline unsigned short qdq(float t, float bm, float scale) {
  float s = t / bm;
  s = s * 6.0f;
  float a = fabsf(s);
  float v;
  if (a <= 0.25f)      v = 0.0f;
  else if (a <= 0.75f) v = 0.5f;
  else if (a <= 1.25f) v = 1.0f;
  else if (a <= 1.75f) v = 1.5f;
  else if (a <= 2.5f)  v = 2.0f;
  else if (a <= 3.5f)  v = 3.0f;
  else if (a <= 5.0f)  v = 4.0f;
  else                 v = 6.0f;
  float q = copysignf(v, s);
  return f2bf_bits(q * scale);
}

// Fused quant+dequant for both tensors. One 8-lane subgroup = one 32-elem block.
__global__ void nvfp4_quant_dq2(const float* __restrict__ x, unsigned short* __restrict__ xq,
                                int nsub_x,
                                const float* __restrict__ w, unsigned short* __restrict__ wq,
                                int nsub_total) {
  int gid = blockIdx.x * blockDim.x + threadIdx.x;
  int sub = gid >> 3;
  if (sub >= nsub_total) return;
  const float* in;
  unsigned short* out;
  if (sub < nsub_x) { in = x; out = xq; }
  else { in = w; out = wq; sub -= nsub_x; }
  int l8 = gid & 7;
  long base = (long)sub * 32 + (long)l8 * 4;
  const float4 v = *(const float4*)(in + base);
  float amax = fmaxf(fmaxf(fabsf(v.x), fabsf(v.y)), fmaxf(fabsf(v.z), fabsf(v.w)));
  amax = fmaxf(amax, __shfl_xor(amax, 1));
  amax = fmaxf(amax, __shfl_xor(amax, 2));
  amax = fmaxf(amax, __shfl_xor(amax, 4));
  float bm = fmaxf(amax, 1e-12f);   // jnp.clip(max, 1e-12)
  float scale = bm / 6.0f;
  ushort4 o;
  o.x = qdq(v.x, bm, scale);
  o.y = qdq(v.y, bm, scale);
  o.z = qdq(v.z, bm, scale);
  o.w = qdq(v.w, bm, scale);
  *(ushort4*)(out + base) = o;
}

// C[M,N] = A[M,K](bf16) * B[N,K]^T(bf16). 64x128 tile, BK=32, 4 waves (2x2),
// each wave 32x64 via 2x4 grid of 16x16x32 MFMA. Grid = 512 blocks -> 2 blocks/CU.
__global__ __launch_bounds__(256, 2) void gemm_bf16_bt(
    const unsigned short* __restrict__ A,  // [M, K]
    const unsigned short* __restrict__ B,  // [N, K]
    float* __restrict__ C, int M, int N) {
  __shared__ unsigned short As[BM * BK];   // 4 KB
  __shared__ unsigned short Bs[BN * BK];   // 8 KB

  const int tid = threadIdx.x;
  const int wave = tid >> 6;
  const int lane = tid & 63;
  const int wm = wave >> 1;       // 0..1  (32-row half)
  const int wn = wave & 1;        // 0..1  (64-col half)
  const int quad = lane >> 4;     // 0..3
  const int r16 = lane & 15;      // 0..15

  const int bm0 = blockIdx.y * BM;
  const int bn0 = blockIdx.x * BN;

  // Staging: 12 chunks of 1 KB (16 rows x 32 k each): A = chunks 0..3, B = 4..11.
  // Each wave issues 3 x 16B global_load_lds per K-step. Lane covers
  // row = chunk*16 + lane/4, k = (lane&3)*8 .. +8; LDS dest = base + lane*16 B.
  const int rstg = lane >> 2;          // 0..15
  const int kstg = (lane & 3) * 8;     // 0,8,16,24

  const unsigned short* gptr[3];
  unsigned short* lptr[3];
#pragma unroll
  for (int s = 0; s < 3; s++) {
    int cc = wave * 3 + s;
    if (cc < 4) {
      gptr[s] = A + (long)(bm0 + cc * 16 + rstg) * KDIM + kstg;
      lptr[s] = As + cc * 512 + lane * 8;
    } else {
      int c2 = cc - 4;
      gptr[s] = B + (long)(bn0 + c2 * 16 + rstg) * KDIM + kstg;
      lptr[s] = Bs + c2 * 512 + lane * 8;
    }
  }

  f32x4 acc[2][4] = {};

  for (int k0 = 0; k0 < KDIM; k0 += BK) {
#pragma unroll
    for (int s = 0; s < 3; s++) {
      __builtin_amdgcn_global_load_lds(
          (const __attribute__((address_space(1))) void*)gptr[s],
          (__attribute__((address_space(3))) void*)lptr[s], 16, 0, 0);
      gptr[s] += BK;
    }

    __syncthreads();

    bf16x8 af[2], bf[4];
#pragma unroll
    for (int i = 0; i < 2; i++) {
      const int arow = wm * 32 + i * 16 + r16;
      af[i] = *(const bf16x8*)(As + arow * BK + quad * 8);
    }
#pragma unroll
    for (int j = 0; j < 4; j++) {
      const int brow = wn * 64 + j * 16 + r16;
      bf[j] = *(const bf16x8*)(Bs + brow * BK + quad * 8);
    }

#pragma unroll
    for (int i = 0; i < 2; i++)
#pragma unroll
      for (int j = 0; j < 4; j++)
        acc[i][j] = __builtin_amdgcn_mfma_f32_16x16x32_bf16(af[i], bf[j], acc[i][j], 0, 0, 0);

    __syncthreads();
  }

  // Epilogue: C/D layout col = lane&15, row = quad*4 + reg
#pragma unroll
  for (int i = 0; i < 2; i++) {
#pragma unroll
    for (int j = 0; j < 4; j++) {
      const int row = bm0 + wm * 32 + i * 16 + quad * 4;
      const int col = bn0 + wn * 64 + j * 16 + r16;
#pragma unroll
      for (int r = 0; r < 4; r++)
        C[(long)(row + r) * N + col] = acc[i][j][r];
    }
  }
}

extern "C" void kernel_launch(void* const* d_in, const int* in_sizes, int n_in,
                              void* d_out, int out_size, void* d_ws, size_t ws_size,
                              hipStream_t stream) {
  const float* x = (const float*)d_in[0];   // [M, K] fp32
  const float* w = (const float*)d_in[1];   // [N, K] fp32
  float* out = (float*)d_out;               // [M, N] fp32

  const int MK = in_sizes[0];
  const int NK = in_sizes[1];
  const int M = MK / KDIM;
  const int N = NK / KDIM;

  unsigned short* xq = (unsigned short*)d_ws;        // [M, K] bf16
  unsigned short* wq = xq + (size_t)MK;              // [N, K] bf16

  const int nsub_x = MK / 32;
  const int nsub_total = nsub_x + NK / 32;
  nvfp4_quant_dq2<<<dim3((nsub_total * 8 + 255) / 256), dim3(256), 0, stream>>>(
      x, xq, nsub_x, w, wq, nsub_total);

  dim3 grid(N / BN, M / BM);
  gemm_bf16_bt<<<grid, dim3(256), 0, stream>>>(xq, wq, out, M, N);
}